// Round 10
// baseline (3046.236 us; speedup 1.0000x reference)
//
#include <hip/hip_runtime.h>

#define NN 100000
#define NNP 100032   // padded to 64-row multiple
#define NE 800000
#define NG 4096
#define HH 97
#define HP 128
#define NB 391   // (NN+255)/256 scan blocks

#define WGF_SET_STRIDE 147456   // elements per GRU weight set (8*3*3*4*512)
#define WCF_LAYER_STRIDE 98304  // elements per conv layer (4*8*3*2*512)
#define LSTR 136                // LDS staging row stride (u16 elems)

typedef unsigned short u16;
typedef unsigned int u32;
typedef __attribute__((ext_vector_type(8))) short short8v;
typedef __attribute__((ext_vector_type(4))) float f32x4;

__device__ __forceinline__ float sigm_(float x){ return 1.f/(1.f+__expf(-x)); }
__device__ __forceinline__ float lrelu01_(float x){ return x>0.f? x : 0.01f*x; }
__device__ __forceinline__ float tanh_(float t){ float e2=__expf(2.f*t); return 1.f-2.f/(e2+1.f); }
__device__ __forceinline__ float b2f(u16 u){ union{u32 i; float f;} t; t.i=(u32)u<<16; return t.f; }
__device__ __forceinline__ u16 f2b(float x){ union{float f; u32 i;} t; t.f=x; u32 r=t.i+0x7FFFu+((t.i>>16)&1u); return (u16)(r>>16); }

__device__ __forceinline__ void stg_bf16x4(u16* p, float v0, float v1, float v2, float v3){
  ushort4 s; s.x = f2b(v0); s.y = f2b(v1); s.z = f2b(v2); s.w = f2b(v3);
  *(ushort4*)p = s;
}

__device__ __forceinline__ f32x4 mfma16(short8v a, short8v b, f32x4 c){
  return __builtin_amdgcn_mfma_f32_16x16x32_bf16(a, b, c, 0, 0, 0);
}

// ============ weight packing ============
// conv: WCF flat = ((((l*4+w)*8+t)*3+ks)*2+term)*512 + lane*8 + e
__global__ void k_pack_convw(const float* __restrict__ Wk, const float* __restrict__ Wq,
                             const float* __restrict__ Wv, const float* __restrict__ Ws,
                             u16* __restrict__ out){
  int idx = blockIdx.x*256 + threadIdx.x;
  if (idx >= 7*4*8*3*2*512) return;
  int e = idx & 7, lane = (idx>>3) & 63;
  int r = idx >> 9;
  int term = r & 1; r >>= 1;
  int ks = r % 3; r /= 3;
  int t = r & 7; r >>= 3;
  int w = r & 3; int l = r >> 2;
  int k = ks*32 + (lane>>4)*8 + e;
  int n = (w*8 + t)*16 + (lane & 15);
  int m = n>>7, h = n & 127;
  float val = 0.f;
  if (k < HH && h < HH){
    const float* W = (m==0)? Wk : (m==1)? Wq : (m==2)? Wv : Ws;
    val = W[l*9409 + k*97 + h];
  }
  u16 hi = f2b(val);
  out[idx] = (term==0)? hi : f2b(val - b2f(hi));
}

// gru: WGF flat = ((((set*8+bt)*3+j)*3+ks)*4+mat)*512 + lane*8 + e
__global__ void k_pack_gruw(const float* __restrict__ gih, const float* __restrict__ ghh,
                            const float* __restrict__ mih, const float* __restrict__ mhh,
                            u16* __restrict__ out){
  int idx = blockIdx.x*256 + threadIdx.x;
  if (idx >= 8*8*3*3*4*512) return;
  int e = idx & 7, lane = (idx>>3) & 63;
  int r = idx >> 9;
  int mat = r & 3; r >>= 2;
  int ks = r % 3; r /= 3;
  int j = r % 3; r /= 3;
  int bt = r & 7; int set = r >> 3;
  int k = ks*32 + (lane>>4)*8 + e;
  int n = (j*8 + bt)*16 + (lane & 15);
  int jg = n>>7, g = n & 127;
  float val = 0.f;
  if (k < HH && g < HH){
    const float* srcp;
    if (mat < 2) srcp = (set < 7)? gih + (size_t)set*28227 : mih;
    else         srcp = (set < 7)? ghh + (size_t)set*28227 : mhh;
    val = srcp[k*291 + jg*97 + g];
  }
  u16 hi = f2b(val);
  out[idx] = ((mat & 1)==0)? hi : f2b(val - b2f(hi));
}

__global__ void k_pack_gatw(const float* __restrict__ gatW, u16* __restrict__ out){
  int idx = blockIdx.x*256 + threadIdx.x;
  if (idx >= 2*4*8*512) return;
  int e = idx & 7, lane = (idx>>3) & 63, t = (idx>>9) & 7;
  int ks = (idx>>12) & 3, term = idx>>14;
  int k = ks*32 + (lane>>4)*8 + e;
  int h = t*16 + (lane & 15);
  float val = (k < HH && h < HH)? gatW[k*97 + h] : 0.f;
  u16 hi = f2b(val);
  out[idx] = (term==0)? hi : f2b(val - b2f(hi));
}

// fp32 row-96 vectors: W96C[7][512], W96I[8][384], W96H[8][384]
__global__ void k_pack_w96(const float* __restrict__ Wk, const float* __restrict__ Wq,
                           const float* __restrict__ Wv, const float* __restrict__ Ws,
                           const float* __restrict__ gih, const float* __restrict__ ghh,
                           const float* __restrict__ mih, const float* __restrict__ mhh,
                           float* __restrict__ out){
  int idx = blockIdx.x*256 + threadIdx.x;
  if (idx < 7*512){
    int l = idx >> 9, c = idx & 511;
    int m = c >> 7, h = c & 127;
    float v = 0.f;
    if (h < HH){
      const float* W = (m==0)? Wk : (m==1)? Wq : (m==2)? Wv : Ws;
      v = W[l*9409 + 96*97 + h];
    }
    out[idx] = v;
  } else if (idx < 7*512 + 8*384){
    int r = idx - 7*512;
    int set = r / 384, n = r % 384;
    int j = n >> 7, g = n & 127;
    float v = 0.f;
    if (g < HH){
      const float* srcp = (set < 7)? gih + (size_t)set*28227 : mih;
      v = srcp[96*291 + j*97 + g];
    }
    out[idx] = v;
  } else if (idx < 7*512 + 16*384){
    int r = idx - 7*512 - 8*384;
    int set = r / 384, n = r % 384;
    int j = n >> 7, g = n & 127;
    float v = 0.f;
    if (g < HH){
      const float* srcp = (set < 7)? ghh + (size_t)set*28227 : mhh;
      v = srcp[96*291 + j*97 + g];
    }
    out[idx] = v;
  }
}

__global__ void k_pack_convb(const float* __restrict__ bk, const float* __restrict__ bq,
                             const float* __restrict__ bv, const float* __restrict__ bs,
                             float* __restrict__ out){
  int idx = blockIdx.x*256 + threadIdx.x;
  if (idx >= 7*512) return;
  int l = idx >> 9, c = idx & 511;
  int m = c >> 7, h = c & 127;
  float v = 0.f;
  if (h < HH){
    const float* B = (m==0)? bk : (m==1)? bq : (m==2)? bv : bs;
    v = B[l*97 + h];
  }
  out[idx] = v;
}

__global__ void k_pack_grub(const float* __restrict__ gbi, const float* __restrict__ gbh,
                            const float* __restrict__ mbi, const float* __restrict__ mbh,
                            float* __restrict__ obi, float* __restrict__ obh){
  int idx = blockIdx.x*256 + threadIdx.x;
  if (idx >= 8*384) return;
  int set = idx / 384, n = idx % 384;
  int j = n>>7, g = n & 127;
  float vi = 0.f, vh = 0.f;
  if (g < HH){
    const float* si = (set < 7)? gbi + set*291 : mbi;
    const float* sh = (set < 7)? gbh + set*291 : mbh;
    vi = si[j*97 + g];
    vh = sh[j*97 + g];
  }
  obi[idx] = vi; obh[idx] = vh;
}

// contiguous region: GATWP[16384] ASRCP[128] ADSTP[128] GBP[128] W2P[128] pad[512]
__global__ void k_pack_misc(const float* __restrict__ gatW, const float* __restrict__ asrc,
                            const float* __restrict__ adst, const float* __restrict__ gatb,
                            const float* __restrict__ l2W, float* __restrict__ out){
  int idx = blockIdx.x*256 + threadIdx.x;
  if (idx < 16384){
    int k = idx >> 7, h = idx & 127;
    out[idx] = (k < HH && h < HH)? gatW[k*97 + h] : 0.f;
  } else if (idx < 16512){
    int h = idx - 16384; out[idx] = (h < HH)? asrc[h] : 0.f;
  } else if (idx < 16640){
    int h = idx - 16512; out[idx] = (h < HH)? adst[h] : 0.f;
  } else if (idx < 16768){
    int h = idx - 16640; out[idx] = (h < HH)? gatb[h] : 0.f;
  } else if (idx < 16896){
    int h = idx - 16768; out[idx] = (h < HH)? l2W[h] : 0.f;
  } else if (idx < 17408){
    out[idx] = 0.f;
  }
}

// ============ graph preprocessing ============
__global__ void k_seg(const int* __restrict__ batch, int* __restrict__ seg){
  int g = blockIdx.x*blockDim.x + threadIdx.x;
  if (g > NG) return;
  int lo = 0, hi = NN;
  while (lo < hi){ int mid = (lo+hi) >> 1; if (batch[mid] < g) lo = mid+1; else hi = mid; }
  seg[g] = lo;
}

__global__ void k_hist(const int* __restrict__ dst, int* __restrict__ cnt){
  int e = blockIdx.x*256 + threadIdx.x;
  if (e < NE) atomicAdd(&cnt[dst[e]], 1);
}

__global__ void k_scan_blk(const int* __restrict__ cnt, int* __restrict__ offs,
                           int* __restrict__ bsum){
  __shared__ int s[256];
  int b = blockIdx.x, t = threadIdx.x, i = b*256 + t;
  int v = (i < NN)? cnt[i] : 0;
  s[t] = v; __syncthreads();
  #pragma unroll
  for (int off = 1; off < 256; off <<= 1){
    int tmp = (t >= off)? s[t-off] : 0;
    __syncthreads();
    s[t] += tmp;
    __syncthreads();
  }
  if (i < NN) offs[i] = s[t] - v;
  if (t == 255) bsum[b] = s[255];
}

__global__ void k_scan_top(int* __restrict__ bsum){
  __shared__ int s[512];
  int t = threadIdx.x;
  int v = (t < NB)? bsum[t] : 0;
  s[t] = v; __syncthreads();
  #pragma unroll
  for (int off = 1; off < 512; off <<= 1){
    int tmp = (t >= off)? s[t-off] : 0;
    __syncthreads();
    s[t] += tmp;
    __syncthreads();
  }
  if (t < NB) bsum[t] = s[t] - v;
}

__global__ void k_scan_add(int* __restrict__ offs, const int* __restrict__ bsum,
                           int* __restrict__ cur){
  int b = blockIdx.x, t = threadIdx.x, i = b*256 + t;
  if (i < NN){ int o = offs[i] + bsum[b]; offs[i] = o; cur[i] = o; }
  if (i == 0) offs[NN] = NE;
}

__global__ void k_scatter(const int* __restrict__ src, const int* __restrict__ dst,
                          int* __restrict__ cur, int* __restrict__ eidx){
  int e = blockIdx.x*256 + threadIdx.x;
  if (e >= NE) return;
  int pos = atomicAdd(&cur[dst[e]], 1);
  eidx[pos] = src[e];
}

// ============ lin1 (covers NNP rows; pad rows -> 0) ============
__global__ __launch_bounds__(256) void k_lin1(const float* __restrict__ x,
    const float* __restrict__ W, const float* __restrict__ b, u16* __restrict__ X0){
  int idx = blockIdx.x*256 + threadIdx.x;
  int n = idx >> 7, c = idx & 127;
  float v = 0.f;
  if (n < NN && c < HH){
    v = b[c];
    #pragma unroll
    for (int k = 0; k < 9; ++k) v += x[n*9 + k]*W[k*HH + c];
    v = lrelu01_(v);
  }
  X0[(size_t)n*HP + c] = f2b(v);
}

// ============ conv GEMM (MFMA): 32 rows/block, occupancy-bounded ============
__global__ __launch_bounds__(256, 4) void k_conv_mfma(const u16* __restrict__ X,
    const u16* __restrict__ WCF_l, const float* __restrict__ biasp,
    const float* __restrict__ W96C, u16* __restrict__ KQV,
    u16* __restrict__ Sh, u16* __restrict__ Sl){
  __shared__ u16 stg[5][32][LSTR];
  int tid = threadIdx.x;
  int w = __builtin_amdgcn_readfirstlane(tid >> 6);
  int lane = tid & 63;
  int lm = lane & 15, ls = lane >> 4;
  int m0 = blockIdx.x*32;
  f32x4 acc[2][8] = {};
  const u16* pw = WCF_l + (size_t)w*24576 + lane*8;
  for (int ks = 0; ks < 3; ++ks){
    short8v aX[2];
    #pragma unroll
    for (int rb = 0; rb < 2; ++rb)
      aX[rb] = *(const short8v*)(X + (size_t)(m0 + rb*16 + lm)*HP + ks*32 + ls*8);
    #pragma unroll
    for (int t = 0; t < 8; ++t){
      const u16* q = pw + ((t*3 + ks) << 10);
      short8v wf0 = *(const short8v*)(q);
      short8v wf1 = *(const short8v*)(q + 512);
      #pragma unroll
      for (int rb = 0; rb < 2; ++rb){
        acc[rb][t] = mfma16(wf0, aX[rb], acc[rb][t]);
        acc[rb][t] = mfma16(wf1, aX[rb], acc[rb][t]);
      }
    }
  }
  // epilogue: bias + k96 rank-1, stage to LDS
  float x96[2];
  #pragma unroll
  for (int rb = 0; rb < 2; ++rb)
    x96[rb] = b2f(X[(size_t)(m0 + rb*16 + lm)*HP + 96]);
  #pragma unroll
  for (int t = 0; t < 8; ++t){
    int c0 = w*128 + t*16 + ls*4;
    float4 bv = *(const float4*)(biasp + c0);
    float4 w96 = *(const float4*)(W96C + c0);
    #pragma unroll
    for (int rb = 0; rb < 2; ++rb){
      int node = rb*16 + lm;
      int co = t*16 + ls*4;
      float v0 = acc[rb][t][0] + bv.x + x96[rb]*w96.x;
      float v1 = acc[rb][t][1] + bv.y + x96[rb]*w96.y;
      float v2 = acc[rb][t][2] + bv.z + x96[rb]*w96.z;
      float v3 = acc[rb][t][3] + bv.w + x96[rb]*w96.w;
      if (w < 3){
        stg_bf16x4(&stg[w][node][co], v0, v1, v2, v3);
      } else {
        u16 h0 = f2b(v0), h1 = f2b(v1), h2 = f2b(v2), h3 = f2b(v3);
        ushort4 hv; hv.x=h0; hv.y=h1; hv.z=h2; hv.w=h3;
        *(ushort4*)&stg[3][node][co] = hv;
        stg_bf16x4(&stg[4][node][co],
                   v0 - b2f(h0), v1 - b2f(h1), v2 - b2f(h2), v3 - b2f(h3));
      }
    }
  }
  __syncthreads();
  // drain: fully-coalesced 16B/lane stores
  if (w < 3){
    #pragma unroll
    for (int it = 0; it < 8; ++it){
      int q = it*64 + lane;
      int node = q >> 4, ch = q & 15;
      *(short8v*)(KQV + (size_t)(m0 + node)*384 + w*128 + ch*8) =
          *(const short8v*)&stg[w][node][ch*8];
    }
  } else {
    #pragma unroll
    for (int it = 0; it < 8; ++it){
      int q = it*64 + lane;
      int node = q >> 4, ch = q & 15;
      *(short8v*)(Sh + (size_t)m0*128 + q*8) = *(const short8v*)&stg[3][node][ch*8];
      *(short8v*)(Sl + (size_t)m0*128 + q*8) = *(const short8v*)&stg[4][node][ch*8];
    }
  }
}

// ============ GRU GEMM+gates (MFMA): 32 rows/block, occupancy-bounded ============
__global__ __launch_bounds__(256, 4) void k_gru_mfma(const u16* __restrict__ Sh_,
    const u16* __restrict__ Sl_, const u16* __restrict__ Xin,
    const u16* __restrict__ WGF_set,
    const float* __restrict__ bihp, const float* __restrict__ bhhp,
    const float* __restrict__ W96I, const float* __restrict__ W96H,
    u16* __restrict__ Xout){
  __shared__ u16 stg[32][LSTR];
  int tid = threadIdx.x;
  int w = __builtin_amdgcn_readfirstlane(tid >> 6);
  int lane = tid & 63;
  int lm = lane & 15, ls = lane >> 4;
  int m0 = blockIdx.x*32;
  f32x4 agi[2][2][3] = {};
  f32x4 agh[2][2][3] = {};
  for (int ks = 0; ks < 3; ++ks){
    short8v aX[2], aSh[2], aSl[2];
    #pragma unroll
    for (int rb = 0; rb < 2; ++rb){
      size_t off = (size_t)(m0 + rb*16 + lm)*HP + ks*32 + ls*8;
      aX[rb]  = *(const short8v*)(Xin + off);
      aSh[rb] = *(const short8v*)(Sh_ + off);
      aSl[rb] = *(const short8v*)(Sl_ + off);
    }
    #pragma unroll
    for (int b = 0; b < 2; ++b){
      const u16* pb = WGF_set + (size_t)(2*w + b)*18432 + lane*8;
      #pragma unroll
      for (int j = 0; j < 3; ++j){
        const u16* q = pb + ((j*3 + ks) << 11);
        short8v fIh = *(const short8v*)(q);
        short8v fIl = *(const short8v*)(q + 512);
        short8v fHh = *(const short8v*)(q + 1024);
        short8v fHl = *(const short8v*)(q + 1536);
        #pragma unroll
        for (int rb = 0; rb < 2; ++rb){
          agi[rb][b][j] = mfma16(fIh, aSh[rb], agi[rb][b][j]);
          agi[rb][b][j] = mfma16(fIl, aSh[rb], agi[rb][b][j]);
          agi[rb][b][j] = mfma16(fIh, aSl[rb], agi[rb][b][j]);
          agh[rb][b][j] = mfma16(fHh, aX[rb], agh[rb][b][j]);
          agh[rb][b][j] = mfma16(fHl, aX[rb], agh[rb][b][j]);
        }
      }
    }
  }
  // epilogue: k=96 exact fp32, gates, stage Xout
  float s96[2], x96[2];
  #pragma unroll
  for (int rb = 0; rb < 2; ++rb){
    size_t o96 = (size_t)(m0 + rb*16 + lm)*HP + 96;
    s96[rb] = b2f(Sh_[o96]) + b2f(Sl_[o96]);
    x96[rb] = b2f(Xin[o96]);
  }
  #pragma unroll
  for (int b = 0; b < 2; ++b){
    int g0 = (2*w + b)*16 + ls*4;
    float4 bi0 = *(const float4*)(bihp + g0);
    float4 bi1 = *(const float4*)(bihp + 128 + g0);
    float4 bi2 = *(const float4*)(bihp + 256 + g0);
    float4 bh0 = *(const float4*)(bhhp + g0);
    float4 bh1 = *(const float4*)(bhhp + 128 + g0);
    float4 bh2 = *(const float4*)(bhhp + 256 + g0);
    float4 wi0 = *(const float4*)(W96I + g0);
    float4 wi1 = *(const float4*)(W96I + 128 + g0);
    float4 wi2 = *(const float4*)(W96I + 256 + g0);
    float4 wh0 = *(const float4*)(W96H + g0);
    float4 wh1 = *(const float4*)(W96H + 128 + g0);
    float4 wh2 = *(const float4*)(W96H + 256 + g0);
    #pragma unroll
    for (int rb = 0; rb < 2; ++rb){
      int node = rb*16 + lm;
      ushort4 xo4 = *(const ushort4*)(Xin + (size_t)(m0 + node)*HP + g0);
      float xo[4] = { b2f(xo4.x), b2f(xo4.y), b2f(xo4.z), b2f(xo4.w) };
      float vout[4];
      #pragma unroll
      for (int r = 0; r < 4; ++r){
        float biv0 = ((const float*)&bi0)[r], biv1 = ((const float*)&bi1)[r], biv2 = ((const float*)&bi2)[r];
        float bhv0 = ((const float*)&bh0)[r], bhv1 = ((const float*)&bh1)[r], bhv2 = ((const float*)&bh2)[r];
        float wiv0 = ((const float*)&wi0)[r], wiv1 = ((const float*)&wi1)[r], wiv2 = ((const float*)&wi2)[r];
        float whv0 = ((const float*)&wh0)[r], whv1 = ((const float*)&wh1)[r], whv2 = ((const float*)&wh2)[r];
        float ir = agi[rb][b][0][r] + biv0 + s96[rb]*wiv0;
        float iz = agi[rb][b][1][r] + biv1 + s96[rb]*wiv1;
        float in_ = agi[rb][b][2][r] + biv2 + s96[rb]*wiv2;
        float hr = agh[rb][b][0][r] + bhv0 + x96[rb]*whv0;
        float hz = agh[rb][b][1][r] + bhv1 + x96[rb]*whv1;
        float hn = agh[rb][b][2][r] + bhv2 + x96[rb]*whv2;
        float rr = sigm_(ir + hr);
        float zz = sigm_(iz + hz);
        float nn2 = tanh_(in_ + rr*hn);
        float v = (1.f - zz)*nn2 + zz*xo[r];
        vout[r] = fmaxf(v, 0.f);
      }
      stg_bf16x4(&stg[node][g0], vout[0], vout[1], vout[2], vout[3]);
    }
  }
  __syncthreads();
  #pragma unroll
  for (int it = 0; it < 2; ++it){
    int q = it*256 + tid;
    int node = q >> 4, ch = q & 15;
    *(short8v*)(Xout + (size_t)m0*128 + q*8) = *(const short8v*)&stg[node][ch*8];
  }
}

// ============ plain 128-col GEMM (MFMA): XS = X @ gatW ============
__global__ __launch_bounds__(256, 4) void k_xs_mfma(const u16* __restrict__ X,
    const u16* __restrict__ GATF, u16* __restrict__ XS){
  __shared__ u16 stg[32][LSTR];
  int tid = threadIdx.x;
  int w = __builtin_amdgcn_readfirstlane(tid >> 6);
  int lane = tid & 63;
  int lm = lane & 15, ls = lane >> 4;
  int m0 = blockIdx.x*32;
  f32x4 acc[2][2] = {};
  for (int ks = 0; ks < 4; ++ks){
    short8v aX[2];
    #pragma unroll
    for (int rb = 0; rb < 2; ++rb){
      int row = m0 + rb*16 + lm;
      aX[rb] = *(const short8v*)(X + (size_t)row*HP + ks*32 + ls*8);
    }
    #pragma unroll
    for (int b = 0; b < 2; ++b){
      int t = 2*w + b;
      short8v bh = *(const short8v*)(GATF + (((size_t)(0*4 + ks)*8 + t)*64 + lane)*8);
      short8v bl = *(const short8v*)(GATF + (((size_t)(1*4 + ks)*8 + t)*64 + lane)*8);
      #pragma unroll
      for (int rb = 0; rb < 2; ++rb){
        acc[rb][b] = mfma16(bh, aX[rb], acc[rb][b]);
        acc[rb][b] = mfma16(bl, aX[rb], acc[rb][b]);
      }
    }
  }
  #pragma unroll
  for (int b = 0; b < 2; ++b){
    int c0 = (2*w + b)*16 + ls*4;
    #pragma unroll
    for (int rb = 0; rb < 2; ++rb){
      int node = rb*16 + lm;
      stg_bf16x4(&stg[node][c0], acc[rb][b][0], acc[rb][b][1], acc[rb][b][2], acc[rb][b][3]);
    }
  }
  __syncthreads();
  #pragma unroll
  for (int it = 0; it < 2; ++it){
    int q = it*256 + tid;
    int node = q >> 4, ch = q & 15;
    *(short8v*)(XS + (size_t)m0*128 + q*8) = *(const short8v*)&stg[node][ch*8];
  }
}

// ============ CSR aggregation (+ residual + ELU + BN) -> Sh/Sl in place ============
__global__ __launch_bounds__(256) void k_agg(const u16* __restrict__ kqv,
    const int* __restrict__ offs, const int* __restrict__ eidx,
    u16* __restrict__ Sh, u16* __restrict__ Sl,
    const float* __restrict__ gamma, const float* __restrict__ beta,
    const float* __restrict__ mean, const float* __restrict__ var, int layer){
  int n = blockIdx.x*4 + (threadIdx.x >> 6);
  if (n >= NN) return;
  int lane = threadIdx.x & 63;
  int c2 = lane*2;
  int lo = offs[n], hi = offs[n+1];
  ushort2 kk = *(const ushort2*)(kqv + (size_t)n*384 + c2);
  float k0 = b2f(kk.x), k1 = b2f(kk.y);
  float a0 = 0.f, a1 = 0.f;
  int i = lo;
  for (; i + 4 <= hi; i += 4){
    int s0 = eidx[i], s1 = eidx[i+1], s2 = eidx[i+2], s3 = eidx[i+3];
    const u16* q0 = kqv + (size_t)s0*384 + 128 + c2;
    const u16* q1 = kqv + (size_t)s1*384 + 128 + c2;
    const u16* q2 = kqv + (size_t)s2*384 + 128 + c2;
    const u16* q3 = kqv + (size_t)s3*384 + 128 + c2;
    ushort2 qa = *(const ushort2*)q0, va = *(const ushort2*)(q0 + 128);
    ushort2 qb = *(const ushort2*)q1, vb = *(const ushort2*)(q1 + 128);
    ushort2 qc = *(const ushort2*)q2, vc = *(const ushort2*)(q2 + 128);
    ushort2 qd = *(const ushort2*)q3, vd = *(const ushort2*)(q3 + 128);
    a0 += b2f(va.x)*sigm_(k0 + b2f(qa.x)); a1 += b2f(va.y)*sigm_(k1 + b2f(qa.y));
    a0 += b2f(vb.x)*sigm_(k0 + b2f(qb.x)); a1 += b2f(vb.y)*sigm_(k1 + b2f(qb.y));
    a0 += b2f(vc.x)*sigm_(k0 + b2f(qc.x)); a1 += b2f(vc.y)*sigm_(k1 + b2f(qc.y));
    a0 += b2f(vd.x)*sigm_(k0 + b2f(qd.x)); a1 += b2f(vd.y)*sigm_(k1 + b2f(qd.y));
  }
  for (; i < hi; ++i){
    int s = eidx[i];
    const u16* qb0 = kqv + (size_t)s*384 + 128 + c2;
    ushort2 qq = *(const ushort2*)qb0;
    ushort2 vv = *(const ushort2*)(qb0 + 128);
    a0 += b2f(vv.x)*sigm_(k0 + b2f(qq.x));
    a1 += b2f(vv.y)*sigm_(k1 + b2f(qq.y));
  }
  u16* shp = Sh + (size_t)n*HP + c2;
  u16* slp = Sl + (size_t)n*HP + c2;
  ushort2 sh2 = *(const ushort2*)shp;
  ushort2 sl2 = *(const ushort2*)slp;
  float v0 = b2f(sh2.x) + b2f(sl2.x) + a0;
  float v1 = b2f(sh2.y) + b2f(sl2.y) + a1;
  v0 = v0 > 0.f ? v0 : (__expf(v0) - 1.f);
  v1 = v1 > 0.f ? v1 : (__expf(v1) - 1.f);
  if (layer > 0){
    int b0 = (layer-1)*97 + c2;
    if (c2 < HH){ float sc = gamma[b0]*rsqrtf(var[b0] + 1e-5f); v0 = (v0 - mean[b0])*sc + beta[b0]; }
    if (c2+1 < HH){ float sc = gamma[b0+1]*rsqrtf(var[b0+1] + 1e-5f); v1 = (v1 - mean[b0+1])*sc + beta[b0+1]; }
  }
  if (c2 >= HH)   v0 = 0.f;
  if (c2+1 >= HH) v1 = 0.f;
  u16 h0 = f2b(v0), h1 = f2b(v1);
  *(ushort2*)shp = make_ushort2(h0, h1);
  *(ushort2*)slp = make_ushort2(f2b(v0 - b2f(h0)), f2b(v1 - b2f(h1)));
}

// ============ readout ============
__global__ __launch_bounds__(128) void k_pool(const int* __restrict__ seg,
    const u16* __restrict__ x, u16* __restrict__ out){
  int g = blockIdx.x, tid = threadIdx.x;
  int lo = seg[g], hi = seg[g+1];
  float acc = 0.f;
  for (int n = lo; n < hi; ++n) acc += b2f(x[(size_t)n*HP + tid]);
  out[(size_t)g*HP + tid] = f2b(fmaxf(acc, 0.f));
}

__global__ __launch_bounds__(256) void k_as(const u16* __restrict__ xs,
    const float* __restrict__ asrcp, float* __restrict__ a_s){
  int t = blockIdx.x*256 + threadIdx.x;
  int n = t >> 6, lane = t & 63;
  float v = b2f(xs[(size_t)n*HP + lane])*asrcp[lane]
          + b2f(xs[(size_t)n*HP + 64 + lane])*asrcp[64 + lane];
  #pragma unroll
  for (int o = 32; o > 0; o >>= 1) v += __shfl_down(v, o);
  if (lane == 0) a_s[n] = v;
}

__global__ __launch_bounds__(128) void k_ad(const u16* __restrict__ out,
    const float* __restrict__ gatwp, const float* __restrict__ adstp, float* __restrict__ ad){
  int g = blockIdx.x, tid = threadIdx.x;
  __shared__ float so[HP];
  __shared__ float red[2];
  so[tid] = b2f(out[(size_t)g*HP + tid]);
  __syncthreads();
  float p = 0.f;
  #pragma unroll 4
  for (int k = 0; k < HP; ++k) p += so[k]*gatwp[k*HP + tid];
  float v = p * adstp[tid];
  #pragma unroll
  for (int o = 32; o > 0; o >>= 1) v += __shfl_down(v, o);
  if ((tid & 63) == 0) red[tid >> 6] = v;
  __syncthreads();
  if (tid == 0) ad[g] = red[0] + red[1];
}

#define ACAP 2048
__global__ __launch_bounds__(128) void k_attn(const int* __restrict__ seg,
    const float* __restrict__ a_s, const float* __restrict__ a_d,
    const u16* __restrict__ xs, const float* __restrict__ gbp,
    u16* __restrict__ hgh, u16* __restrict__ hgl){
  int g = blockIdx.x, tid = threadIdx.x;
  int lo = seg[g], hi = seg[g+1], cnt = hi - lo;
  float ad = a_d[g];
  __shared__ float sa[ACAP];
  __shared__ float red[2];
  float mloc = -3.4e38f;
  for (int i = tid; i < cnt; i += 128){
    float al = lrelu01_(a_s[lo+i] + ad);
    if (i < ACAP) sa[i] = al;
    mloc = fmaxf(mloc, al);
  }
  #pragma unroll
  for (int o = 32; o > 0; o >>= 1) mloc = fmaxf(mloc, __shfl_down(mloc, o));
  if ((tid & 63) == 0) red[tid >> 6] = mloc;
  __syncthreads();
  float mm = fmaxf(red[0], red[1]);
  __syncthreads();
  float sloc = 0.f;
  for (int i = tid; i < cnt; i += 128){
    float al = (i < ACAP)? sa[i] : lrelu01_(a_s[lo+i] + ad);
    float e = __expf(al - mm);
    if (i < ACAP) sa[i] = e;
    sloc += e;
  }
  #pragma unroll
  for (int o = 32; o > 0; o >>= 1) sloc += __shfl_down(sloc, o);
  if ((tid & 63) == 0) red[tid >> 6] = sloc;
  __syncthreads();
  float ss = red[0] + red[1];
  float inv = (cnt > 0 && ss != 0.f)? 1.f/ss : 0.f;
  __syncthreads();
  float accv = 0.f;
  for (int i = 0; i < cnt; ++i){
    float e = (i < ACAP)? sa[i] : __expf(lrelu01_(a_s[lo+i] + ad) - mm);
    accv += (e*inv) * b2f(xs[(size_t)(lo+i)*HP + tid]);
  }
  float hgv = accv + gbp[tid];
  hgv = hgv > 0.f ? hgv : (__expf(hgv) - 1.f);
  u16 hb = f2b(hgv);
  hgh[(size_t)g*HP + tid] = hb;
  hgl[(size_t)g*HP + tid] = f2b(hgv - b2f(hb));
}

__global__ __launch_bounds__(64) void k_final(const u16* __restrict__ out,
    const float* __restrict__ w2p, const float* __restrict__ l2b, float* __restrict__ y){
  int g = blockIdx.x, lane = threadIdx.x;
  float v = b2f(out[(size_t)g*HP + lane])*w2p[lane]
          + b2f(out[(size_t)g*HP + 64 + lane])*w2p[64 + lane];
  #pragma unroll
  for (int o = 32; o > 0; o >>= 1) v += __shfl_down(v, o);
  if (lane == 0) y[g] = v + l2b[0];
}

// ============ host ============
extern "C" void kernel_launch(void* const* d_in, const int* in_sizes, int n_in,
                              void* d_out, int out_size, void* d_ws, size_t ws_size,
                              hipStream_t stream){
  const float* x_in  = (const float*)d_in[0];
  const int*   ei    = (const int*)d_in[1];
  const int*   batch = (const int*)d_in[2];
  const float* lin1W = (const float*)d_in[4];
  const float* lin1b = (const float*)d_in[5];
  const float* cWk = (const float*)d_in[6];
  const float* cWq = (const float*)d_in[7];
  const float* cWv = (const float*)d_in[8];
  const float* cWs = (const float*)d_in[9];
  const float* cbk = (const float*)d_in[10];
  const float* cbq = (const float*)d_in[11];
  const float* cbv = (const float*)d_in[12];
  const float* cbs = (const float*)d_in[13];
  const float* gWih = (const float*)d_in[14];
  const float* gWhh = (const float*)d_in[15];
  const float* gbih = (const float*)d_in[16];
  const float* gbhh = (const float*)d_in[17];
  const float* bng = (const float*)d_in[18];
  const float* bnb = (const float*)d_in[19];
  const float* bnm = (const float*)d_in[20];
  const float* bnv = (const float*)d_in[21];
  const float* gatW  = (const float*)d_in[22];
  const float* gasrc = (const float*)d_in[23];
  const float* gadst = (const float*)d_in[24];
  const float* gatb  = (const float*)d_in[25];
  const float* mWih = (const float*)d_in[26];
  const float* mWhh = (const float*)d_in[27];
  const float* mbih = (const float*)d_in[28];
  const float* mbhh = (const float*)d_in[29];
  const float* l2W = (const float*)d_in[30];
  const float* l2b = (const float*)d_in[31];
  const int* src = ei;
  const int* dst = ei + NE;

  char* base = (char*)d_ws;
  size_t off = 0;
  auto alloc = [&](size_t nbytes)->char*{
    char* p = base + off; off = (off + nbytes + 255) & ~(size_t)255; return p; };

  u16*  WCF  = (u16*)alloc((size_t)7*WCF_LAYER_STRIDE*2);
  u16*  WGF  = (u16*)alloc((size_t)8*WGF_SET_STRIDE*2);
  u16*  GATF = (u16*)alloc((size_t)2*4*8*512*2);
  float* W96  = (float*)alloc((size_t)(7*512 + 16*384)*4);  // W96C | W96I | W96H
  float* BCONVP = (float*)alloc(7*512*4);
  float* BIHP   = (float*)alloc(8*384*4);
  float* BHHP   = (float*)alloc(8*384*4);
  float* GATWP  = (float*)alloc(17408*4);
  float* ASRCP = GATWP + 16384;
  float* ADSTP = GATWP + 16512;
  float* GBP   = GATWP + 16640;
  float* W2P   = GATWP + 16768;
  u16*  X0  = (u16*)alloc((size_t)NNP*HP*2);
  u16*  X1  = (u16*)alloc((size_t)NNP*HP*2);
  u16*  KQV = (u16*)alloc((size_t)NNP*384*2);
  u16*  Sh  = (u16*)alloc((size_t)NNP*HP*2);
  u16*  Sl  = (u16*)alloc((size_t)NNP*HP*2);
  float* AS_ = (float*)alloc((size_t)NN*4);
  float* AD_ = (float*)alloc((size_t)NG*4);
  u16*  OUTA = (u16*)alloc((size_t)NG*HP*2);
  u16*  OUTB = (u16*)alloc((size_t)NG*HP*2);
  u16*  HGH  = (u16*)alloc((size_t)NG*HP*2);
  u16*  HGL  = (u16*)alloc((size_t)NG*HP*2);
  int*  SEG  = (int*)alloc((size_t)(NG+1)*4);
  int*  CNT  = (int*)alloc((size_t)NN*4);
  int*  OFFS = (int*)alloc((size_t)(NN+1)*4);
  int*  CUR  = (int*)alloc((size_t)NN*4);
  int*  EIDX = (int*)alloc((size_t)NE*4);
  int*  BSUM = (int*)alloc((size_t)NB*4);

  float* W96C = W96;
  float* W96I = W96 + 7*512;
  float* W96H = W96 + 7*512 + 8*384;

  if (ws_size < off){
    hipMemsetAsync(d_out, 0, (size_t)out_size*sizeof(float), stream);
    return;
  }

  // ---- one-time packing + graph prep ----
  k_pack_convw<<<(7*WCF_LAYER_STRIDE)/256,256,0,stream>>>(cWk,cWq,cWv,cWs,WCF);
  k_pack_gruw<<<(8*WGF_SET_STRIDE)/256,256,0,stream>>>(gWih,gWhh,mWih,mWhh,WGF);
  k_pack_gatw<<<(2*4*8*512+255)/256,256,0,stream>>>(gatW,GATF);
  k_pack_w96<<<(7*512+16*384+255)/256,256,0,stream>>>(cWk,cWq,cWv,cWs,gWih,gWhh,mWih,mWhh,W96);
  k_pack_convb<<<(7*512+255)/256,256,0,stream>>>(cbk,cbq,cbv,cbs,BCONVP);
  k_pack_grub<<<(8*384+255)/256,256,0,stream>>>(gbih,gbhh,mbih,mbhh,BIHP,BHHP);
  k_pack_misc<<<68,256,0,stream>>>(gatW,gasrc,gadst,gatb,l2W,GATWP);
  k_lin1<<<(NNP*HP)/256,256,0,stream>>>(x_in,lin1W,lin1b,X0);
  k_seg<<<(NG+1+255)/256,256,0,stream>>>(batch,SEG);

  hipMemsetAsync(CNT, 0, (size_t)NN*4, stream);
  k_hist<<<(NE+255)/256,256,0,stream>>>(dst, CNT);
  k_scan_blk<<<NB,256,0,stream>>>(CNT, OFFS, BSUM);
  k_scan_top<<<1,512,0,stream>>>(BSUM);
  k_scan_add<<<NB,256,0,stream>>>(OFFS, BSUM, CUR);
  k_scatter<<<(NE+255)/256,256,0,stream>>>(src, dst, CUR, EIDX);

  // ---- 7 conv+gru layers ----
  for (int l = 0; l < 7; ++l){
    u16* Xin  = (l & 1)? X1 : X0;
    u16* Xout = (l & 1)? X0 : X1;
    k_conv_mfma<<<NNP/32,256,0,stream>>>(Xin, WCF + (size_t)l*WCF_LAYER_STRIDE,
                                         BCONVP + l*512, W96C + l*512, KQV, Sh, Sl);
    k_agg<<<(NN+3)/4,256,0,stream>>>(KQV, OFFS, EIDX, Sh, Sl, bng, bnb, bnm, bnv, l);
    k_gru_mfma<<<NNP/32,256,0,stream>>>(Sh, Sl, Xin, WGF + (size_t)l*WGF_SET_STRIDE,
                                        BIHP + l*384, BHHP + l*384,
                                        W96I + l*384, W96H + l*384, Xout);
  }
  u16* XF = X1;

  // ---- readout ----
  k_pool<<<NG,128,0,stream>>>(SEG, XF, OUTA);
  u16* XS = KQV;
  k_xs_mfma<<<NNP/32,256,0,stream>>>(XF, GATF, XS);
  k_as<<<(NN*64)/256,256,0,stream>>>(XS, ASRCP, AS_);

  u16* cur = OUTA; u16* nxt = OUTB;
  for (int s = 0; s < 7; ++s){
    k_ad<<<NG,128,0,stream>>>(cur, GATWP, ADSTP, AD_);
    k_attn<<<NG,128,0,stream>>>(SEG, AS_, AD_, XS, GBP, HGH, HGL);
    k_gru_mfma<<<NG/32,256,0,stream>>>(HGH, HGL, cur, WGF + (size_t)7*WGF_SET_STRIDE,
                                       BIHP + 7*384, BHHP + 7*384,
                                       W96I + 7*384, W96H + 7*384, nxt);
    u16* t = cur; cur = nxt; nxt = t;
  }
  k_final<<<NG,64,0,stream>>>(cur, W2P, l2b, (float*)d_out);
}

// Round 12
// 2210.813 us; speedup vs baseline: 1.3779x; 1.3779x over previous
//
#include <hip/hip_runtime.h>

#define NN 100000
#define NNP 100032   // padded to 64-row multiple
#define NE 800000
#define NG 4096
#define HH 97
#define HP 128
#define NB 391   // (NN+255)/256 scan blocks

#define WGF_SET_STRIDE 147456   // elements per GRU weight set (8*3*3*4*512)
#define WCF_LAYER_STRIDE 98304  // elements per conv layer (32*3*2*512)
#define LSTR 136                // LDS staging row stride (u16 elems)

typedef unsigned short u16;
typedef unsigned int u32;
typedef __attribute__((ext_vector_type(8))) short short8v;
typedef __attribute__((ext_vector_type(4))) float f32x4;

__device__ __forceinline__ float sigm_(float x){ return 1.f/(1.f+__expf(-x)); }
__device__ __forceinline__ float lrelu01_(float x){ return x>0.f? x : 0.01f*x; }
__device__ __forceinline__ float tanh_(float t){ float e2=__expf(2.f*t); return 1.f-2.f/(e2+1.f); }
__device__ __forceinline__ float b2f(u16 u){ union{u32 i; float f;} t; t.i=(u32)u<<16; return t.f; }
__device__ __forceinline__ u16 f2b(float x){ union{float f; u32 i;} t; t.f=x; u32 r=t.i+0x7FFFu+((t.i>>16)&1u); return (u16)(r>>16); }

__device__ __forceinline__ void stg_bf16x4(u16* p, float v0, float v1, float v2, float v3){
  ushort4 s; s.x = f2b(v0); s.y = f2b(v1); s.z = f2b(v2); s.w = f2b(v3);
  *(ushort4*)p = s;
}

__device__ __forceinline__ f32x4 mfma16(short8v a, short8v b, f32x4 c){
  return __builtin_amdgcn_mfma_f32_16x16x32_bf16(a, b, c, 0, 0, 0);
}

// ============ weight packing ============
// conv: WCF flat = (((l*32 + tg)*3 + ks)*2 + term)*512 + lane*8 + e   (tg = global tile 0..31)
__global__ void k_pack_convw(const float* __restrict__ Wk, const float* __restrict__ Wq,
                             const float* __restrict__ Wv, const float* __restrict__ Ws,
                             u16* __restrict__ out){
  int idx = blockIdx.x*256 + threadIdx.x;
  if (idx >= 7*32*3*2*512) return;
  int e = idx & 7, lane = (idx>>3) & 63;
  int r = idx >> 9;
  int term = r & 1; r >>= 1;
  int ks = r % 3; r /= 3;
  int tg = r & 31; int l = r >> 5;
  int k = ks*32 + (lane>>4)*8 + e;
  int n = tg*16 + (lane & 15);
  int m = n>>7, h = n & 127;
  float val = 0.f;
  if (k < HH && h < HH){
    const float* W = (m==0)? Wk : (m==1)? Wq : (m==2)? Wv : Ws;
    val = W[l*9409 + k*97 + h];
  }
  u16 hi = f2b(val);
  out[idx] = (term==0)? hi : f2b(val - b2f(hi));
}

// gru: WGF flat = ((((set*8+bt)*3+j)*3+ks)*4+mat)*512 + lane*8 + e
__global__ void k_pack_gruw(const float* __restrict__ gih, const float* __restrict__ ghh,
                            const float* __restrict__ mih, const float* __restrict__ mhh,
                            u16* __restrict__ out){
  int idx = blockIdx.x*256 + threadIdx.x;
  if (idx >= 8*8*3*3*4*512) return;
  int e = idx & 7, lane = (idx>>3) & 63;
  int r = idx >> 9;
  int mat = r & 3; r >>= 2;
  int ks = r % 3; r /= 3;
  int j = r % 3; r /= 3;
  int bt = r & 7; int set = r >> 3;
  int k = ks*32 + (lane>>4)*8 + e;
  int n = (j*8 + bt)*16 + (lane & 15);
  int jg = n>>7, g = n & 127;
  float val = 0.f;
  if (k < HH && g < HH){
    const float* srcp;
    if (mat < 2) srcp = (set < 7)? gih + (size_t)set*28227 : mih;
    else         srcp = (set < 7)? ghh + (size_t)set*28227 : mhh;
    val = srcp[k*291 + jg*97 + g];
  }
  u16 hi = f2b(val);
  out[idx] = ((mat & 1)==0)? hi : f2b(val - b2f(hi));
}

__global__ void k_pack_gatw(const float* __restrict__ gatW, u16* __restrict__ out){
  int idx = blockIdx.x*256 + threadIdx.x;
  if (idx >= 2*4*8*512) return;
  int e = idx & 7, lane = (idx>>3) & 63, t = (idx>>9) & 7;
  int ks = (idx>>12) & 3, term = idx>>14;
  int k = ks*32 + (lane>>4)*8 + e;
  int h = t*16 + (lane & 15);
  float val = (k < HH && h < HH)? gatW[k*97 + h] : 0.f;
  u16 hi = f2b(val);
  out[idx] = (term==0)? hi : f2b(val - b2f(hi));
}

// fp32 row-96 vectors: W96C[7][512], W96I[8][384], W96H[8][384]
__global__ void k_pack_w96(const float* __restrict__ Wk, const float* __restrict__ Wq,
                           const float* __restrict__ Wv, const float* __restrict__ Ws,
                           const float* __restrict__ gih, const float* __restrict__ ghh,
                           const float* __restrict__ mih, const float* __restrict__ mhh,
                           float* __restrict__ out){
  int idx = blockIdx.x*256 + threadIdx.x;
  if (idx < 7*512){
    int l = idx >> 9, c = idx & 511;
    int m = c >> 7, h = c & 127;
    float v = 0.f;
    if (h < HH){
      const float* W = (m==0)? Wk : (m==1)? Wq : (m==2)? Wv : Ws;
      v = W[l*9409 + 96*97 + h];
    }
    out[idx] = v;
  } else if (idx < 7*512 + 8*384){
    int r = idx - 7*512;
    int set = r / 384, n = r % 384;
    int j = n >> 7, g = n & 127;
    float v = 0.f;
    if (g < HH){
      const float* srcp = (set < 7)? gih + (size_t)set*28227 : mih;
      v = srcp[96*291 + j*97 + g];
    }
    out[idx] = v;
  } else if (idx < 7*512 + 16*384){
    int r = idx - 7*512 - 8*384;
    int set = r / 384, n = r % 384;
    int j = n >> 7, g = n & 127;
    float v = 0.f;
    if (g < HH){
      const float* srcp = (set < 7)? ghh + (size_t)set*28227 : mhh;
      v = srcp[96*291 + j*97 + g];
    }
    out[idx] = v;
  }
}

__global__ void k_pack_convb(const float* __restrict__ bk, const float* __restrict__ bq,
                             const float* __restrict__ bv, const float* __restrict__ bs,
                             float* __restrict__ out){
  int idx = blockIdx.x*256 + threadIdx.x;
  if (idx >= 7*512) return;
  int l = idx >> 9, c = idx & 511;
  int m = c >> 7, h = c & 127;
  float v = 0.f;
  if (h < HH){
    const float* B = (m==0)? bk : (m==1)? bq : (m==2)? bv : bs;
    v = B[l*97 + h];
  }
  out[idx] = v;
}

__global__ void k_pack_grub(const float* __restrict__ gbi, const float* __restrict__ gbh,
                            const float* __restrict__ mbi, const float* __restrict__ mbh,
                            float* __restrict__ obi, float* __restrict__ obh){
  int idx = blockIdx.x*256 + threadIdx.x;
  if (idx >= 8*384) return;
  int set = idx / 384, n = idx % 384;
  int j = n>>7, g = n & 127;
  float vi = 0.f, vh = 0.f;
  if (g < HH){
    const float* si = (set < 7)? gbi + set*291 : mbi;
    const float* sh = (set < 7)? gbh + set*291 : mbh;
    vi = si[j*97 + g];
    vh = sh[j*97 + g];
  }
  obi[idx] = vi; obh[idx] = vh;
}

// contiguous region: GATWP[16384] ASRCP[128] ADSTP[128] GBP[128] W2P[128] pad[512]
__global__ void k_pack_misc(const float* __restrict__ gatW, const float* __restrict__ asrc,
                            const float* __restrict__ adst, const float* __restrict__ gatb,
                            const float* __restrict__ l2W, float* __restrict__ out){
  int idx = blockIdx.x*256 + threadIdx.x;
  if (idx < 16384){
    int k = idx >> 7, h = idx & 127;
    out[idx] = (k < HH && h < HH)? gatW[k*97 + h] : 0.f;
  } else if (idx < 16512){
    int h = idx - 16384; out[idx] = (h < HH)? asrc[h] : 0.f;
  } else if (idx < 16640){
    int h = idx - 16512; out[idx] = (h < HH)? adst[h] : 0.f;
  } else if (idx < 16768){
    int h = idx - 16640; out[idx] = (h < HH)? gatb[h] : 0.f;
  } else if (idx < 16896){
    int h = idx - 16768; out[idx] = (h < HH)? l2W[h] : 0.f;
  } else if (idx < 17408){
    out[idx] = 0.f;
  }
}

// ============ graph preprocessing ============
__global__ void k_seg(const int* __restrict__ batch, int* __restrict__ seg){
  int g = blockIdx.x*blockDim.x + threadIdx.x;
  if (g > NG) return;
  int lo = 0, hi = NN;
  while (lo < hi){ int mid = (lo+hi) >> 1; if (batch[mid] < g) lo = mid+1; else hi = mid; }
  seg[g] = lo;
}

__global__ void k_hist(const int* __restrict__ dst, int* __restrict__ cnt){
  int e = blockIdx.x*256 + threadIdx.x;
  if (e < NE) atomicAdd(&cnt[dst[e]], 1);
}

__global__ void k_scan_blk(const int* __restrict__ cnt, int* __restrict__ offs,
                           int* __restrict__ bsum){
  __shared__ int s[256];
  int b = blockIdx.x, t = threadIdx.x, i = b*256 + t;
  int v = (i < NN)? cnt[i] : 0;
  s[t] = v; __syncthreads();
  #pragma unroll
  for (int off = 1; off < 256; off <<= 1){
    int tmp = (t >= off)? s[t-off] : 0;
    __syncthreads();
    s[t] += tmp;
    __syncthreads();
  }
  if (i < NN) offs[i] = s[t] - v;
  if (t == 255) bsum[b] = s[255];
}

__global__ void k_scan_top(int* __restrict__ bsum){
  __shared__ int s[512];
  int t = threadIdx.x;
  int v = (t < NB)? bsum[t] : 0;
  s[t] = v; __syncthreads();
  #pragma unroll
  for (int off = 1; off < 512; off <<= 1){
    int tmp = (t >= off)? s[t-off] : 0;
    __syncthreads();
    s[t] += tmp;
    __syncthreads();
  }
  if (t < NB) bsum[t] = s[t] - v;
}

__global__ void k_scan_add(int* __restrict__ offs, const int* __restrict__ bsum,
                           int* __restrict__ cur){
  int b = blockIdx.x, t = threadIdx.x, i = b*256 + t;
  if (i < NN){ int o = offs[i] + bsum[b]; offs[i] = o; cur[i] = o; }
  if (i == 0) offs[NN] = NE;
}

__global__ void k_scatter(const int* __restrict__ src, const int* __restrict__ dst,
                          int* __restrict__ cur, int* __restrict__ eidx){
  int e = blockIdx.x*256 + threadIdx.x;
  if (e >= NE) return;
  int pos = atomicAdd(&cur[dst[e]], 1);
  eidx[pos] = src[e];
}

// ============ lin1 (covers NNP rows; pad rows -> 0) ============
__global__ __launch_bounds__(256) void k_lin1(const float* __restrict__ x,
    const float* __restrict__ W, const float* __restrict__ b, u16* __restrict__ X0){
  int idx = blockIdx.x*256 + threadIdx.x;
  int n = idx >> 7, c = idx & 127;
  float v = 0.f;
  if (n < NN && c < HH){
    v = b[c];
    #pragma unroll
    for (int k = 0; k < 9; ++k) v += x[n*9 + k]*W[k*HH + c];
    v = lrelu01_(v);
  }
  X0[(size_t)n*HP + c] = f2b(v);
}

// ============ conv GEMM (MFMA): 32 rows/block, 8 waves, wave owns 4 col-tiles ============
__global__ __launch_bounds__(512) void k_conv_mfma(const u16* __restrict__ X,
    const u16* __restrict__ WCF_l, const float* __restrict__ biasp,
    const float* __restrict__ W96C, u16* __restrict__ KQV,
    u16* __restrict__ Sh, u16* __restrict__ Sl){
  __shared__ u16 stg[5][32][LSTR];
  int tid = threadIdx.x;
  int w = __builtin_amdgcn_readfirstlane(tid >> 6);   // 0..7
  int lane = tid & 63;
  int lm = lane & 15, ls = lane >> 4;
  int m0 = blockIdx.x*32;
  f32x4 acc[2][4] = {};
  const u16* pw = WCF_l + (size_t)w*12288 + lane*8;   // 4 tiles * 3 ks * 2 terms * 512
  for (int ks = 0; ks < 3; ++ks){
    short8v aX[2];
    #pragma unroll
    for (int rb = 0; rb < 2; ++rb)
      aX[rb] = *(const short8v*)(X + (size_t)(m0 + rb*16 + lm)*HP + ks*32 + ls*8);
    short8v wf[4][2];
    #pragma unroll
    for (int tt = 0; tt < 4; ++tt){
      const u16* q = pw + ((tt*3 + ks) << 10);
      wf[tt][0] = *(const short8v*)(q);
      wf[tt][1] = *(const short8v*)(q + 512);
    }
    #pragma unroll
    for (int tt = 0; tt < 4; ++tt)
      #pragma unroll
      for (int rb = 0; rb < 2; ++rb){
        acc[rb][tt] = mfma16(wf[tt][0], aX[rb], acc[rb][tt]);
        acc[rb][tt] = mfma16(wf[tt][1], aX[rb], acc[rb][tt]);
      }
  }
  // epilogue: bias + k96 rank-1, stage to LDS
  float x96[2];
  #pragma unroll
  for (int rb = 0; rb < 2; ++rb)
    x96[rb] = b2f(X[(size_t)(m0 + rb*16 + lm)*HP + 96]);
  #pragma unroll
  for (int tt = 0; tt < 4; ++tt){
    int tg = w*4 + tt;
    int c0g = tg*16 + ls*4;      // global col 0..511
    float4 bv = *(const float4*)(biasp + c0g);
    float4 w96 = *(const float4*)(W96C + c0g);
    int slice = tg >> 3;
    int co = (tg & 7)*16 + ls*4; // col within 128-slice
    #pragma unroll
    for (int rb = 0; rb < 2; ++rb){
      int node = rb*16 + lm;
      float v0 = acc[rb][tt][0] + bv.x + x96[rb]*w96.x;
      float v1 = acc[rb][tt][1] + bv.y + x96[rb]*w96.y;
      float v2 = acc[rb][tt][2] + bv.z + x96[rb]*w96.z;
      float v3 = acc[rb][tt][3] + bv.w + x96[rb]*w96.w;
      if (slice < 3){
        stg_bf16x4(&stg[slice][node][co], v0, v1, v2, v3);
      } else {
        u16 h0 = f2b(v0), h1 = f2b(v1), h2 = f2b(v2), h3 = f2b(v3);
        ushort4 hv; hv.x=h0; hv.y=h1; hv.z=h2; hv.w=h3;
        *(ushort4*)&stg[3][node][co] = hv;
        stg_bf16x4(&stg[4][node][co],
                   v0 - b2f(h0), v1 - b2f(h1), v2 - b2f(h2), v3 - b2f(h3));
      }
    }
  }
  __syncthreads();
  // drain: 5 slices * 512 chunks of 8 u16 each = 2560 chunks, 512 threads, 5 iters
  #pragma unroll
  for (int it = 0; it < 5; ++it){
    int idx = it*512 + tid;
    int s = idx >> 9;           // slice 0..4
    int r = idx & 511;          // chunk within slice (node*16 + ch)
    int node = r >> 4, ch = r & 15;
    short8v v = *(const short8v*)&stg[s][node][ch*8];
    if (s < 3)      *(short8v*)(KQV + (size_t)(m0 + node)*384 + s*128 + ch*8) = v;
    else if (s == 3)*(short8v*)(Sh + (size_t)m0*128 + r*8) = v;
    else            *(short8v*)(Sl + (size_t)m0*128 + r*8) = v;
  }
}

// ============ GRU GEMM+gates (MFMA): 32 rows/block, 8 waves, wave owns 1 col-tile ============
__global__ __launch_bounds__(512) void k_gru_mfma(const u16* __restrict__ Sh_,
    const u16* __restrict__ Sl_, const u16* __restrict__ Xin,
    const u16* __restrict__ WGF_set,
    const float* __restrict__ bihp, const float* __restrict__ bhhp,
    const float* __restrict__ W96I, const float* __restrict__ W96H,
    u16* __restrict__ Xout){
  __shared__ u16 stg[32][LSTR];
  int tid = threadIdx.x;
  int w = __builtin_amdgcn_readfirstlane(tid >> 6);   // bt = w, 0..7
  int lane = tid & 63;
  int lm = lane & 15, ls = lane >> 4;
  int m0 = blockIdx.x*32;
  f32x4 agi[2][3] = {};
  f32x4 agh[2][3] = {};
  const u16* pb = WGF_set + (size_t)w*18432 + lane*8;
  for (int ks = 0; ks < 3; ++ks){
    short8v aX[2], aSh[2], aSl[2];
    #pragma unroll
    for (int rb = 0; rb < 2; ++rb){
      size_t off = (size_t)(m0 + rb*16 + lm)*HP + ks*32 + ls*8;
      aX[rb]  = *(const short8v*)(Xin + off);
      aSh[rb] = *(const short8v*)(Sh_ + off);
      aSl[rb] = *(const short8v*)(Sl_ + off);
    }
    #pragma unroll
    for (int j = 0; j < 3; ++j){
      const u16* q = pb + ((j*3 + ks) << 11);
      short8v fIh = *(const short8v*)(q);
      short8v fIl = *(const short8v*)(q + 512);
      short8v fHh = *(const short8v*)(q + 1024);
      short8v fHl = *(const short8v*)(q + 1536);
      #pragma unroll
      for (int rb = 0; rb < 2; ++rb){
        agi[rb][j] = mfma16(fIh, aSh[rb], agi[rb][j]);
        agi[rb][j] = mfma16(fIl, aSh[rb], agi[rb][j]);
        agi[rb][j] = mfma16(fIh, aSl[rb], agi[rb][j]);
        agh[rb][j] = mfma16(fHh, aX[rb], agh[rb][j]);
        agh[rb][j] = mfma16(fHl, aX[rb], agh[rb][j]);
      }
    }
  }
  // epilogue: k=96 exact fp32, gates (4 consecutive g per lane), stage Xout
  float s96[2], x96[2];
  #pragma unroll
  for (int rb = 0; rb < 2; ++rb){
    size_t o96 = (size_t)(m0 + rb*16 + lm)*HP + 96;
    s96[rb] = b2f(Sh_[o96]) + b2f(Sl_[o96]);
    x96[rb] = b2f(Xin[o96]);
  }
  int g0 = w*16 + ls*4;
  float4 bi0 = *(const float4*)(bihp + g0);
  float4 bi1 = *(const float4*)(bihp + 128 + g0);
  float4 bi2 = *(const float4*)(bihp + 256 + g0);
  float4 bh0 = *(const float4*)(bhhp + g0);
  float4 bh1 = *(const float4*)(bhhp + 128 + g0);
  float4 bh2 = *(const float4*)(bhhp + 256 + g0);
  float4 wi0 = *(const float4*)(W96I + g0);
  float4 wi1 = *(const float4*)(W96I + 128 + g0);
  float4 wi2 = *(const float4*)(W96I + 256 + g0);
  float4 wh0 = *(const float4*)(W96H + g0);
  float4 wh1 = *(const float4*)(W96H + 128 + g0);
  float4 wh2 = *(const float4*)(W96H + 256 + g0);
  #pragma unroll
  for (int rb = 0; rb < 2; ++rb){
    int node = rb*16 + lm;
    ushort4 xo4 = *(const ushort4*)(Xin + (size_t)(m0 + node)*HP + g0);
    float xo[4] = { b2f(xo4.x), b2f(xo4.y), b2f(xo4.z), b2f(xo4.w) };
    float vout[4];
    #pragma unroll
    for (int r = 0; r < 4; ++r){
      float biv0 = ((const float*)&bi0)[r], biv1 = ((const float*)&bi1)[r], biv2 = ((const float*)&bi2)[r];
      float bhv0 = ((const float*)&bh0)[r], bhv1 = ((const float*)&bh1)[r], bhv2 = ((const float*)&bh2)[r];
      float wiv0 = ((const float*)&wi0)[r], wiv1 = ((const float*)&wi1)[r], wiv2 = ((const float*)&wi2)[r];
      float whv0 = ((const float*)&wh0)[r], whv1 = ((const float*)&wh1)[r], whv2 = ((const float*)&wh2)[r];
      float ir = agi[rb][0][r] + biv0 + s96[rb]*wiv0;
      float iz = agi[rb][1][r] + biv1 + s96[rb]*wiv1;
      float in_ = agi[rb][2][r] + biv2 + s96[rb]*wiv2;
      float hr = agh[rb][0][r] + bhv0 + x96[rb]*whv0;
      float hz = agh[rb][1][r] + bhv1 + x96[rb]*whv1;
      float hn = agh[rb][2][r] + bhv2 + x96[rb]*whv2;
      float rr = sigm_(ir + hr);
      float zz = sigm_(iz + hz);
      float nn2 = tanh_(in_ + rr*hn);
      float v = (1.f - zz)*nn2 + zz*xo[r];
      vout[r] = fmaxf(v, 0.f);
    }
    stg_bf16x4(&stg[node][g0], vout[0], vout[1], vout[2], vout[3]);
  }
  __syncthreads();
  // drain: 512 chunks of 8 u16 (32 nodes * 128 ch), 512 threads, 1 chunk each
  {
    int node = tid >> 4, ch = tid & 15;
    *(short8v*)(Xout + (size_t)m0*128 + tid*8) = *(const short8v*)&stg[node][ch*8];
  }
}

// ============ plain 128-col GEMM (MFMA): XS = X @ gatW ============
__global__ __launch_bounds__(256) void k_xs_mfma(const u16* __restrict__ X,
    const u16* __restrict__ GATF, u16* __restrict__ XS){
  __shared__ u16 stg[32][LSTR];
  int tid = threadIdx.x;
  int w = __builtin_amdgcn_readfirstlane(tid >> 6);
  int lane = tid & 63;
  int lm = lane & 15, ls = lane >> 4;
  int m0 = blockIdx.x*32;
  f32x4 acc[2][2] = {};
  for (int ks = 0; ks < 4; ++ks){
    short8v aX[2];
    #pragma unroll
    for (int rb = 0; rb < 2; ++rb){
      int row = m0 + rb*16 + lm;
      aX[rb] = *(const short8v*)(X + (size_t)row*HP + ks*32 + ls*8);
    }
    #pragma unroll
    for (int b = 0; b < 2; ++b){
      int t = 2*w + b;
      short8v bh = *(const short8v*)(GATF + (((size_t)(0*4 + ks)*8 + t)*64 + lane)*8);
      short8v bl = *(const short8v*)(GATF + (((size_t)(1*4 + ks)*8 + t)*64 + lane)*8);
      #pragma unroll
      for (int rb = 0; rb < 2; ++rb){
        acc[rb][b] = mfma16(bh, aX[rb], acc[rb][b]);
        acc[rb][b] = mfma16(bl, aX[rb], acc[rb][b]);
      }
    }
  }
  #pragma unroll
  for (int b = 0; b < 2; ++b){
    int c0 = (2*w + b)*16 + ls*4;
    #pragma unroll
    for (int rb = 0; rb < 2; ++rb){
      int node = rb*16 + lm;
      stg_bf16x4(&stg[node][c0], acc[rb][b][0], acc[rb][b][1], acc[rb][b][2], acc[rb][b][3]);
    }
  }
  __syncthreads();
  #pragma unroll
  for (int it = 0; it < 2; ++it){
    int q = it*256 + tid;
    int node = q >> 4, ch = q & 15;
    *(short8v*)(XS + (size_t)m0*128 + q*8) = *(const short8v*)&stg[node][ch*8];
  }
}

// ============ CSR aggregation (+ residual + ELU + BN) -> Sh/Sl in place ============
__global__ __launch_bounds__(256) void k_agg(const u16* __restrict__ kqv,
    const int* __restrict__ offs, const int* __restrict__ eidx,
    u16* __restrict__ Sh, u16* __restrict__ Sl,
    const float* __restrict__ gamma, const float* __restrict__ beta,
    const float* __restrict__ mean, const float* __restrict__ var, int layer){
  int n = blockIdx.x*4 + (threadIdx.x >> 6);
  if (n >= NN) return;
  int lane = threadIdx.x & 63;
  int c2 = lane*2;
  int lo = offs[n], hi = offs[n+1];
  ushort2 kk = *(const ushort2*)(kqv + (size_t)n*384 + c2);
  float k0 = b2f(kk.x), k1 = b2f(kk.y);
  float a0 = 0.f, a1 = 0.f;
  int i = lo;
  for (; i + 4 <= hi; i += 4){
    int s0 = eidx[i], s1 = eidx[i+1], s2 = eidx[i+2], s3 = eidx[i+3];
    const u16* q0 = kqv + (size_t)s0*384 + 128 + c2;
    const u16* q1 = kqv + (size_t)s1*384 + 128 + c2;
    const u16* q2 = kqv + (size_t)s2*384 + 128 + c2;
    const u16* q3 = kqv + (size_t)s3*384 + 128 + c2;
    ushort2 qa = *(const ushort2*)q0, va = *(const ushort2*)(q0 + 128);
    ushort2 qb = *(const ushort2*)q1, vb = *(const ushort2*)(q1 + 128);
    ushort2 qc = *(const ushort2*)q2, vc = *(const ushort2*)(q2 + 128);
    ushort2 qd = *(const ushort2*)q3, vd = *(const ushort2*)(q3 + 128);
    a0 += b2f(va.x)*sigm_(k0 + b2f(qa.x)); a1 += b2f(va.y)*sigm_(k1 + b2f(qa.y));
    a0 += b2f(vb.x)*sigm_(k0 + b2f(qb.x)); a1 += b2f(vb.y)*sigm_(k1 + b2f(qb.y));
    a0 += b2f(vc.x)*sigm_(k0 + b2f(qc.x)); a1 += b2f(vc.y)*sigm_(k1 + b2f(qc.y));
    a0 += b2f(vd.x)*sigm_(k0 + b2f(qd.x)); a1 += b2f(vd.y)*sigm_(k1 + b2f(qd.y));
  }
  for (; i < hi; ++i){
    int s = eidx[i];
    const u16* qb0 = kqv + (size_t)s*384 + 128 + c2;
    ushort2 qq = *(const ushort2*)qb0;
    ushort2 vv = *(const ushort2*)(qb0 + 128);
    a0 += b2f(vv.x)*sigm_(k0 + b2f(qq.x));
    a1 += b2f(vv.y)*sigm_(k1 + b2f(qq.y));
  }
  u16* shp = Sh + (size_t)n*HP + c2;
  u16* slp = Sl + (size_t)n*HP + c2;
  ushort2 sh2 = *(const ushort2*)shp;
  ushort2 sl2 = *(const ushort2*)slp;
  float v0 = b2f(sh2.x) + b2f(sl2.x) + a0;
  float v1 = b2f(sh2.y) + b2f(sl2.y) + a1;
  v0 = v0 > 0.f ? v0 : (__expf(v0) - 1.f);
  v1 = v1 > 0.f ? v1 : (__expf(v1) - 1.f);
  if (layer > 0){
    int b0 = (layer-1)*97 + c2;
    if (c2 < HH){ float sc = gamma[b0]*rsqrtf(var[b0] + 1e-5f); v0 = (v0 - mean[b0])*sc + beta[b0]; }
    if (c2+1 < HH){ float sc = gamma[b0+1]*rsqrtf(var[b0+1] + 1e-5f); v1 = (v1 - mean[b0+1])*sc + beta[b0+1]; }
  }
  if (c2 >= HH)   v0 = 0.f;
  if (c2+1 >= HH) v1 = 0.f;
  u16 h0 = f2b(v0), h1 = f2b(v1);
  *(ushort2*)shp = make_ushort2(h0, h1);
  *(ushort2*)slp = make_ushort2(f2b(v0 - b2f(h0)), f2b(v1 - b2f(h1)));
}

// ============ readout ============
__global__ __launch_bounds__(128) void k_pool(const int* __restrict__ seg,
    const u16* __restrict__ x, u16* __restrict__ out){
  int g = blockIdx.x, tid = threadIdx.x;
  int lo = seg[g], hi = seg[g+1];
  float acc = 0.f;
  for (int n = lo; n < hi; ++n) acc += b2f(x[(size_t)n*HP + tid]);
  out[(size_t)g*HP + tid] = f2b(fmaxf(acc, 0.f));
}

__global__ __launch_bounds__(256) void k_as(const u16* __restrict__ xs,
    const float* __restrict__ asrcp, float* __restrict__ a_s){
  int t = blockIdx.x*256 + threadIdx.x;
  int n = t >> 6, lane = t & 63;
  float v = b2f(xs[(size_t)n*HP + lane])*asrcp[lane]
          + b2f(xs[(size_t)n*HP + 64 + lane])*asrcp[64 + lane];
  #pragma unroll
  for (int o = 32; o > 0; o >>= 1) v += __shfl_down(v, o);
  if (lane == 0) a_s[n] = v;
}

__global__ __launch_bounds__(128) void k_ad(const u16* __restrict__ out,
    const float* __restrict__ gatwp, const float* __restrict__ adstp, float* __restrict__ ad){
  int g = blockIdx.x, tid = threadIdx.x;
  __shared__ float so[HP];
  __shared__ float red[2];
  so[tid] = b2f(out[(size_t)g*HP + tid]);
  __syncthreads();
  float p = 0.f;
  #pragma unroll 4
  for (int k = 0; k < HP; ++k) p += so[k]*gatwp[k*HP + tid];
  float v = p * adstp[tid];
  #pragma unroll
  for (int o = 32; o > 0; o >>= 1) v += __shfl_down(v, o);
  if ((tid & 63) == 0) red[tid >> 6] = v;
  __syncthreads();
  if (tid == 0) ad[g] = red[0] + red[1];
}

#define ACAP 2048
__global__ __launch_bounds__(128) void k_attn(const int* __restrict__ seg,
    const float* __restrict__ a_s, const float* __restrict__ a_d,
    const u16* __restrict__ xs, const float* __restrict__ gbp,
    u16* __restrict__ hgh, u16* __restrict__ hgl){
  int g = blockIdx.x, tid = threadIdx.x;
  int lo = seg[g], hi = seg[g+1], cnt = hi - lo;
  float ad = a_d[g];
  __shared__ float sa[ACAP];
  __shared__ float red[2];
  float mloc = -3.4e38f;
  for (int i = tid; i < cnt; i += 128){
    float al = lrelu01_(a_s[lo+i] + ad);
    if (i < ACAP) sa[i] = al;
    mloc = fmaxf(mloc, al);
  }
  #pragma unroll
  for (int o = 32; o > 0; o >>= 1) mloc = fmaxf(mloc, __shfl_down(mloc, o));
  if ((tid & 63) == 0) red[tid >> 6] = mloc;
  __syncthreads();
  float mm = fmaxf(red[0], red[1]);
  __syncthreads();
  float sloc = 0.f;
  for (int i = tid; i < cnt; i += 128){
    float al = (i < ACAP)? sa[i] : lrelu01_(a_s[lo+i] + ad);
    float e = __expf(al - mm);
    if (i < ACAP) sa[i] = e;
    sloc += e;
  }
  #pragma unroll
  for (int o = 32; o > 0; o >>= 1) sloc += __shfl_down(sloc, o);
  if ((tid & 63) == 0) red[tid >> 6] = sloc;
  __syncthreads();
  float ss = red[0] + red[1];
  float inv = (cnt > 0 && ss != 0.f)? 1.f/ss : 0.f;
  __syncthreads();
  float accv = 0.f;
  for (int i = 0; i < cnt; ++i){
    float e = (i < ACAP)? sa[i] : __expf(lrelu01_(a_s[lo+i] + ad) - mm);
    accv += (e*inv) * b2f(xs[(size_t)(lo+i)*HP + tid]);
  }
  float hgv = accv + gbp[tid];
  hgv = hgv > 0.f ? hgv : (__expf(hgv) - 1.f);
  u16 hb = f2b(hgv);
  hgh[(size_t)g*HP + tid] = hb;
  hgl[(size_t)g*HP + tid] = f2b(hgv - b2f(hb));
}

__global__ __launch_bounds__(64) void k_final(const u16* __restrict__ out,
    const float* __restrict__ w2p, const float* __restrict__ l2b, float* __restrict__ y){
  int g = blockIdx.x, lane = threadIdx.x;
  float v = b2f(out[(size_t)g*HP + lane])*w2p[lane]
          + b2f(out[(size_t)g*HP + 64 + lane])*w2p[64 + lane];
  #pragma unroll
  for (int o = 32; o > 0; o >>= 1) v += __shfl_down(v, o);
  if (lane == 0) y[g] = v + l2b[0];
}

// ============ host ============
extern "C" void kernel_launch(void* const* d_in, const int* in_sizes, int n_in,
                              void* d_out, int out_size, void* d_ws, size_t ws_size,
                              hipStream_t stream){
  const float* x_in  = (const float*)d_in[0];
  const int*   ei    = (const int*)d_in[1];
  const int*   batch = (const int*)d_in[2];
  const float* lin1W = (const float*)d_in[4];
  const float* lin1b = (const float*)d_in[5];
  const float* cWk = (const float*)d_in[6];
  const float* cWq = (const float*)d_in[7];
  const float* cWv = (const float*)d_in[8];
  const float* cWs = (const float*)d_in[9];
  const float* cbk = (const float*)d_in[10];
  const float* cbq = (const float*)d_in[11];
  const float* cbv = (const float*)d_in[12];
  const float* cbs = (const float*)d_in[13];
  const float* gWih = (const float*)d_in[14];
  const float* gWhh = (const float*)d_in[15];
  const float* gbih = (const float*)d_in[16];
  const float* gbhh = (const float*)d_in[17];
  const float* bng = (const float*)d_in[18];
  const float* bnb = (const float*)d_in[19];
  const float* bnm = (const float*)d_in[20];
  const float* bnv = (const float*)d_in[21];
  const float* gatW  = (const float*)d_in[22];
  const float* gasrc = (const float*)d_in[23];
  const float* gadst = (const float*)d_in[24];
  const float* gatb  = (const float*)d_in[25];
  const float* mWih = (const float*)d_in[26];
  const float* mWhh = (const float*)d_in[27];
  const float* mbih = (const float*)d_in[28];
  const float* mbhh = (const float*)d_in[29];
  const float* l2W = (const float*)d_in[30];
  const float* l2b = (const float*)d_in[31];
  const int* src = ei;
  const int* dst = ei + NE;

  char* base = (char*)d_ws;
  size_t off = 0;
  auto alloc = [&](size_t nbytes)->char*{
    char* p = base + off; off = (off + nbytes + 255) & ~(size_t)255; return p; };

  u16*  WCF  = (u16*)alloc((size_t)7*WCF_LAYER_STRIDE*2);
  u16*  WGF  = (u16*)alloc((size_t)8*WGF_SET_STRIDE*2);
  u16*  GATF = (u16*)alloc((size_t)2*4*8*512*2);
  float* W96  = (float*)alloc((size_t)(7*512 + 16*384)*4);  // W96C | W96I | W96H
  float* BCONVP = (float*)alloc(7*512*4);
  float* BIHP   = (float*)alloc(8*384*4);
  float* BHHP   = (float*)alloc(8*384*4);
  float* GATWP  = (float*)alloc(17408*4);
  float* ASRCP = GATWP + 16384;
  float* ADSTP = GATWP + 16512;
  float* GBP   = GATWP + 16640;
  float* W2P   = GATWP + 16768;
  u16*  X0  = (u16*)alloc((size_t)NNP*HP*2);
  u16*  X1  = (u16*)alloc((size_t)NNP*HP*2);
  u16*  KQV = (u16*)alloc((size_t)NNP*384*2);
  u16*  Sh  = (u16*)alloc((size_t)NNP*HP*2);
  u16*  Sl  = (u16*)alloc((size_t)NNP*HP*2);
  float* AS_ = (float*)alloc((size_t)NN*4);
  float* AD_ = (float*)alloc((size_t)NG*4);
  u16*  OUTA = (u16*)alloc((size_t)NG*HP*2);
  u16*  OUTB = (u16*)alloc((size_t)NG*HP*2);
  u16*  HGH  = (u16*)alloc((size_t)NG*HP*2);
  u16*  HGL  = (u16*)alloc((size_t)NG*HP*2);
  int*  SEG  = (int*)alloc((size_t)(NG+1)*4);
  int*  CNT  = (int*)alloc((size_t)NN*4);
  int*  OFFS = (int*)alloc((size_t)(NN+1)*4);
  int*  CUR  = (int*)alloc((size_t)NN*4);
  int*  EIDX = (int*)alloc((size_t)NE*4);
  int*  BSUM = (int*)alloc((size_t)NB*4);

  float* W96C = W96;
  float* W96I = W96 + 7*512;
  float* W96H = W96 + 7*512 + 8*384;

  if (ws_size < off){
    hipMemsetAsync(d_out, 0, (size_t)out_size*sizeof(float), stream);
    return;
  }

  // ---- one-time packing + graph prep ----
  k_pack_convw<<<(7*WCF_LAYER_STRIDE)/256,256,0,stream>>>(cWk,cWq,cWv,cWs,WCF);
  k_pack_gruw<<<(8*WGF_SET_STRIDE)/256,256,0,stream>>>(gWih,gWhh,mWih,mWhh,WGF);
  k_pack_gatw<<<(2*4*8*512+255)/256,256,0,stream>>>(gatW,GATF);
  k_pack_w96<<<(7*512+16*384+255)/256,256,0,stream>>>(cWk,cWq,cWv,cWs,gWih,gWhh,mWih,mWhh,W96);
  k_pack_convb<<<(7*512+255)/256,256,0,stream>>>(cbk,cbq,cbv,cbs,BCONVP);
  k_pack_grub<<<(8*384+255)/256,256,0,stream>>>(gbih,gbhh,mbih,mbhh,BIHP,BHHP);
  k_pack_misc<<<68,256,0,stream>>>(gatW,gasrc,gadst,gatb,l2W,GATWP);
  k_lin1<<<(NNP*HP)/256,256,0,stream>>>(x_in,lin1W,lin1b,X0);
  k_seg<<<(NG+1+255)/256,256,0,stream>>>(batch,SEG);

  hipMemsetAsync(CNT, 0, (size_t)NN*4, stream);
  k_hist<<<(NE+255)/256,256,0,stream>>>(dst, CNT);
  k_scan_blk<<<NB,256,0,stream>>>(CNT, OFFS, BSUM);
  k_scan_top<<<1,512,0,stream>>>(BSUM);
  k_scan_add<<<NB,256,0,stream>>>(OFFS, BSUM, CUR);
  k_scatter<<<(NE+255)/256,256,0,stream>>>(src, dst, CUR, EIDX);

  // ---- 7 conv+gru layers ----
  for (int l = 0; l < 7; ++l){
    u16* Xin  = (l & 1)? X1 : X0;
    u16* Xout = (l & 1)? X0 : X1;
    k_conv_mfma<<<NNP/32,512,0,stream>>>(Xin, WCF + (size_t)l*WCF_LAYER_STRIDE,
                                         BCONVP + l*512, W96C + l*512, KQV, Sh, Sl);
    k_agg<<<(NN+3)/4,256,0,stream>>>(KQV, OFFS, EIDX, Sh, Sl, bng, bnb, bnm, bnv, l);
    k_gru_mfma<<<NNP/32,512,0,stream>>>(Sh, Sl, Xin, WGF + (size_t)l*WGF_SET_STRIDE,
                                        BIHP + l*384, BHHP + l*384,
                                        W96I + l*384, W96H + l*384, Xout);
  }
  u16* XF = X1;

  // ---- readout ----
  k_pool<<<NG,128,0,stream>>>(SEG, XF, OUTA);
  u16* XS = KQV;
  k_xs_mfma<<<NNP/32,256,0,stream>>>(XF, GATF, XS);
  k_as<<<(NN*64)/256,256,0,stream>>>(XS, ASRCP, AS_);

  u16* cur = OUTA; u16* nxt = OUTB;
  for (int s = 0; s < 7; ++s){
    k_ad<<<NG,128,0,stream>>>(cur, GATWP, ADSTP, AD_);
    k_attn<<<NG,128,0,stream>>>(SEG, AS_, AD_, XS, GBP, HGH, HGL);
    k_gru_mfma<<<NG/32,512,0,stream>>>(HGH, HGL, cur, WGF + (size_t)7*WGF_SET_STRIDE,
                                       BIHP + 7*384, BHHP + 7*384,
                                       W96I + 7*384, W96H + 7*384, nxt);
    u16* t = cur; cur = nxt; nxt = t;
  }
  k_final<<<NG,64,0,stream>>>(cur, W2P, l2b, (float*)d_out);
}